// Round 1
// baseline (1667.095 us; speedup 1.0000x reference)
//
#include <hip/hip_runtime.h>
#include <hip/hip_bf16.h>

#define NTOT   16384
#define NFEAT  128
#define NHID   128
#define NCLASS 40

typedef __attribute__((ext_vector_type(8))) short          bf16x8s;
typedef __attribute__((ext_vector_type(4))) float          f32x4v;
typedef __attribute__((ext_vector_type(2))) float          f32x2v;
typedef __attribute__((ext_vector_type(4))) unsigned short u16x4v;
typedef __attribute__((ext_vector_type(2))) unsigned int   u32x2v;
typedef __attribute__((ext_vector_type(4))) unsigned int   u32x4v;

// fp32 -> bf16, round-to-nearest-even (inputs are finite; no NaN handling needed)
__device__ __forceinline__ unsigned short f2b(float f) {
  unsigned int u = __float_as_uint(f);
  u = u + 0x7fffu + ((u >> 16) & 1u);
  return (unsigned short)(u >> 16);
}

// ---------------------------------------------------------------------------
// Kernel 1: x [16384][128] f32  ->  xT [128][16384] bf16 (transposed, RTN)
// ---------------------------------------------------------------------------
__global__ __launch_bounds__(256) void xpose_cvt(
    const float* __restrict__ x, unsigned short* __restrict__ xT)
{
  __shared__ unsigned short T[128 * 68];   // pad 64->68 to break bank conflicts
  const int tid = threadIdx.x;
  const int i0  = blockIdx.x << 6;         // 64 rows per block
#pragma unroll
  for (int it = 0; it < 8; ++it) {
    const int c   = (it << 8) + tid;
    const int row = c >> 5;                // 0..63
    const int f4  = (c & 31) << 2;         // 0..124
    const f32x4v v = *(const f32x4v*)(x + (size_t)(i0 + row) * NFEAT + f4);
#pragma unroll
    for (int u = 0; u < 4; ++u) T[(f4 + u) * 68 + row] = f2b(v[u]);
  }
  __syncthreads();
  const int f    = tid >> 1;               // 0..127
  const int half = (tid & 1) << 5;         // 0 / 32
  const unsigned short* src = T + f * 68 + half;
  unsigned short*       dst = xT + (size_t)f * NTOT + i0 + half;
#pragma unroll
  for (int j = 0; j < 8; ++j)
    *(u32x2v*)(dst + (j << 2)) = *(const u32x2v*)(src + (j << 2));
}

// ---------------------------------------------------------------------------
// Kernel 2/4: support_partial[part] = adj[m0:m0+128, kchunk] @ BT^T
//   adj: [16384][16384] f32 (converted to bf16 in staging)
//   BT : [128][16384] bf16 (B operand, K-contiguous rows)
//   out: [P][16384][128] f32 partials
// 128x128 tile, BK=64, 4 waves (2x2 of 64x64), mfma_f32_16x16x32_bf16.
// LDS rows are 128B; XOR-swizzle slot ^= row&7 -> <=2-way conflicts on b128.
// ---------------------------------------------------------------------------
__global__ __launch_bounds__(256) void gemm_adj(
    const float* __restrict__ adj,
    const unsigned short* __restrict__ BT,
    float* __restrict__ outp,
    int kchunk)
{
  __shared__ short As[128 * 64];
  __shared__ short Bs[128 * 64];
  const int tid  = threadIdx.x;
  const int lane = tid & 63;
  const int wv   = tid >> 6;
  const int wr   = (wv >> 1) << 6;       // wave row offset: 0/64
  const int wc   = (wv & 1) << 6;        // wave col offset: 0/64
  const int m0   = blockIdx.x << 7;
  const int part = blockIdx.y;
  const int kstart = part * kchunk;

  f32x4v acc[4][4];
#pragma unroll
  for (int m = 0; m < 4; ++m)
#pragma unroll
    for (int n = 0; n < 4; ++n) acc[m][n] = (f32x4v)(0.0f);

  const int arow = tid >> 4;             // + 16*i
  const int acol = (tid & 15) << 2;      // 4 floats
  const int brow = tid >> 3;             // + 32*i
  const int bcol = (tid & 7) << 3;       // 8 bf16

  const int nk = kchunk >> 6;
  for (int kt = 0; kt < nk; ++kt) {
    const int k0 = kstart + (kt << 6);
    // stage A: 128x64 f32 -> bf16 (swizzled)
#pragma unroll
    for (int i = 0; i < 8; ++i) {
      const int row = arow + (i << 4);
      const f32x4v v = *(const f32x4v*)(adj + (size_t)(m0 + row) * NTOT + k0 + acol);
      u32x2v pk;
      pk[0] = ((unsigned int)f2b(v[1]) << 16) | f2b(v[0]);
      pk[1] = ((unsigned int)f2b(v[3]) << 16) | f2b(v[2]);
      const int so = (row << 6) + ((((acol >> 3) ^ (row & 7)) << 3)) + (acol & 7);
      *(u32x2v*)(As + so) = pk;
    }
    // stage B: 128x64 bf16 (already bf16, swizzled)
#pragma unroll
    for (int i = 0; i < 4; ++i) {
      const int n = brow + (i << 5);
      const u32x4v v = *(const u32x4v*)(BT + (size_t)n * NTOT + k0 + bcol);
      const int so = (n << 6) + (((bcol >> 3) ^ (n & 7)) << 3);
      *(u32x4v*)(Bs + so) = v;
    }
    __syncthreads();
#pragma unroll
    for (int kk = 0; kk < 2; ++kk) {
      const int slot = (kk << 2) + (lane >> 4);
      bf16x8s a[4], b[4];
#pragma unroll
      for (int m = 0; m < 4; ++m) {
        const int row = wr + (m << 4) + (lane & 15);
        a[m] = *(const bf16x8s*)(As + (row << 6) + ((slot ^ (row & 7)) << 3));
      }
#pragma unroll
      for (int n = 0; n < 4; ++n) {
        const int col = wc + (n << 4) + (lane & 15);
        b[n] = *(const bf16x8s*)(Bs + (col << 6) + ((slot ^ (col & 7)) << 3));
      }
#pragma unroll
      for (int m = 0; m < 4; ++m)
#pragma unroll
        for (int n = 0; n < 4; ++n)
          acc[m][n] = __builtin_amdgcn_mfma_f32_16x16x32_bf16(a[m], b[n], acc[m][n], 0, 0, 0);
    }
    __syncthreads();
  }
  // epilogue: C/D layout col=lane&15, row=(lane>>4)*4+i  [m89-verified]
  float* out = outp + (size_t)part * NTOT * NHID;
  const int rbase = m0 + wr + ((lane >> 4) << 2);
  const int cbase = wc + (lane & 15);
#pragma unroll
  for (int m = 0; m < 4; ++m)
#pragma unroll
    for (int n = 0; n < 4; ++n)
#pragma unroll
      for (int i = 0; i < 4; ++i)
        out[(size_t)(rbase + (m << 4) + i) * NHID + cbase + (n << 4)] = acc[m][n][i];
}

// ---------------------------------------------------------------------------
// Kernel 3: h1 = relu([x | sum_p supp_p] @ W1 + b1)   (fp32 VALU, exactish)
//   writes h1 f32 [16384][128] and h1T bf16 [128][16384]
// ---------------------------------------------------------------------------
__global__ __launch_bounds__(256) void layer1_kernel(
    const float* __restrict__ x, const float* __restrict__ supp, int P,
    const float* __restrict__ W1, const float* __restrict__ b1,
    float* __restrict__ h1out, unsigned short* __restrict__ h1T)
{
  __shared__ float in_t[64 * 260];       // [row][0..127]=x, [128..255]=supp-sum
  const int tid = threadIdx.x;
  const int i0  = blockIdx.x << 6;
#pragma unroll
  for (int it = 0; it < 8; ++it) {
    const int c   = (it << 8) + tid;
    const int row = c >> 5;
    const int f4  = (c & 31) << 2;
    const size_t gidx = (size_t)(i0 + row) * NHID + f4;
    *(f32x4v*)(&in_t[row * 260 + f4]) = *(const f32x4v*)(x + gidx);
    f32x4v s = (f32x4v)(0.0f);
    for (int p = 0; p < P; ++p)
      s += *(const f32x4v*)(supp + (size_t)p * NTOT * NHID + gidx);
    *(f32x4v*)(&in_t[row * 260 + 128 + f4]) = s;
  }
  __syncthreads();
  const int j0 = (tid & 15) << 3;        // 8 output cols
  const int r0 = (tid >> 4) << 2;        // 4 rows
  float accv[4][8];
#pragma unroll
  for (int r = 0; r < 4; ++r)
#pragma unroll
    for (int u = 0; u < 8; ++u) accv[r][u] = 0.0f;

  for (int f = 0; f < 256; f += 4) {
    f32x4v inr[4];
#pragma unroll
    for (int r = 0; r < 4; ++r) inr[r] = *(const f32x4v*)(&in_t[(r0 + r) * 260 + f]);
#pragma unroll
    for (int ff = 0; ff < 4; ++ff) {
      const f32x4v wA = *(const f32x4v*)(W1 + (size_t)(f + ff) * NHID + j0);
      const f32x4v wB = *(const f32x4v*)(W1 + (size_t)(f + ff) * NHID + j0 + 4);
#pragma unroll
      for (int r = 0; r < 4; ++r) {
        const float iv = inr[r][ff];
#pragma unroll
        for (int u = 0; u < 4; ++u) {
          accv[r][u]     = fmaf(iv, wA[u], accv[r][u]);
          accv[r][4 + u] = fmaf(iv, wB[u], accv[r][4 + u]);
        }
      }
    }
  }
  float hrelu[4][8];
#pragma unroll
  for (int r = 0; r < 4; ++r) {
#pragma unroll
    for (int u = 0; u < 8; ++u) {
      float v = accv[r][u] + b1[j0 + u];
      hrelu[r][u] = v > 0.0f ? v : 0.0f;
    }
    f32x4v o0, o1;
#pragma unroll
    for (int u = 0; u < 4; ++u) { o0[u] = hrelu[r][u]; o1[u] = hrelu[r][4 + u]; }
    *(f32x4v*)(h1out + (size_t)(i0 + r0 + r) * NHID + j0)     = o0;
    *(f32x4v*)(h1out + (size_t)(i0 + r0 + r) * NHID + j0 + 4) = o1;
  }
#pragma unroll
  for (int u = 0; u < 8; ++u) {
    u16x4v pk;
#pragma unroll
    for (int r = 0; r < 4; ++r) pk[r] = f2b(hrelu[r][u]);
    *(u16x4v*)(h1T + (size_t)(j0 + u) * NTOT + i0 + r0) = pk;
  }
}

// ---------------------------------------------------------------------------
// Kernel 5: h2 = relu([h1 | sum supp2] @ W2 + b2); logits = h2@Wl+bl;
//           log_probs = log_softmax(logits)
// ---------------------------------------------------------------------------
__global__ __launch_bounds__(256) void layer2_head(
    const float* __restrict__ h1, const float* __restrict__ supp, int P,
    const float* __restrict__ W2, const float* __restrict__ b2,
    const float* __restrict__ Wl, const float* __restrict__ bl,
    float* __restrict__ h2out, float* __restrict__ logout, float* __restrict__ lpout)
{
  __shared__ float in_t[64 * 260];
  __shared__ float h2t[64 * 132];
  const int tid = threadIdx.x;
  const int i0  = blockIdx.x << 6;
#pragma unroll
  for (int it = 0; it < 8; ++it) {
    const int c   = (it << 8) + tid;
    const int row = c >> 5;
    const int f4  = (c & 31) << 2;
    const size_t gidx = (size_t)(i0 + row) * NHID + f4;
    *(f32x4v*)(&in_t[row * 260 + f4]) = *(const f32x4v*)(h1 + gidx);
    f32x4v s = (f32x4v)(0.0f);
    for (int p = 0; p < P; ++p)
      s += *(const f32x4v*)(supp + (size_t)p * NTOT * NHID + gidx);
    *(f32x4v*)(&in_t[row * 260 + 128 + f4]) = s;
  }
  __syncthreads();
  const int j0 = (tid & 15) << 3;
  const int r0 = (tid >> 4) << 2;
  float accv[4][8];
#pragma unroll
  for (int r = 0; r < 4; ++r)
#pragma unroll
    for (int u = 0; u < 8; ++u) accv[r][u] = 0.0f;

  for (int f = 0; f < 256; f += 4) {
    f32x4v inr[4];
#pragma unroll
    for (int r = 0; r < 4; ++r) inr[r] = *(const f32x4v*)(&in_t[(r0 + r) * 260 + f]);
#pragma unroll
    for (int ff = 0; ff < 4; ++ff) {
      const f32x4v wA = *(const f32x4v*)(W2 + (size_t)(f + ff) * NHID + j0);
      const f32x4v wB = *(const f32x4v*)(W2 + (size_t)(f + ff) * NHID + j0 + 4);
#pragma unroll
      for (int r = 0; r < 4; ++r) {
        const float iv = inr[r][ff];
#pragma unroll
        for (int u = 0; u < 4; ++u) {
          accv[r][u]     = fmaf(iv, wA[u], accv[r][u]);
          accv[r][4 + u] = fmaf(iv, wB[u], accv[r][4 + u]);
        }
      }
    }
  }
#pragma unroll
  for (int r = 0; r < 4; ++r) {
    f32x4v o0, o1;
#pragma unroll
    for (int u = 0; u < 8; ++u) {
      float v = accv[r][u] + b2[j0 + u];
      v = v > 0.0f ? v : 0.0f;
      h2t[(r0 + r) * 132 + j0 + u] = v;
      if (u < 4) o0[u] = v; else o1[u - 4] = v;
    }
    *(f32x4v*)(h2out + (size_t)(i0 + r0 + r) * NHID + j0)     = o0;
    *(f32x4v*)(h2out + (size_t)(i0 + r0 + r) * NHID + j0 + 4) = o1;
  }
  __syncthreads();
  // logits: thread -> (row r, 10 classes), 4 threads per row
  const int r  = tid >> 2;
  const int c0 = (tid & 3) * 10;
  float lg[10];
#pragma unroll
  for (int k = 0; k < 10; ++k) lg[k] = bl[c0 + k];
  for (int h = 0; h < 128; ++h) {
    const float hv = h2t[r * 132 + h];
#pragma unroll
    for (int k = 0; k < 5; ++k) {
      const f32x2v w = *(const f32x2v*)(Wl + (size_t)h * NCLASS + c0 + (k << 1));
      lg[2 * k]     = fmaf(hv, w[0], lg[2 * k]);
      lg[2 * k + 1] = fmaf(hv, w[1], lg[2 * k + 1]);
    }
  }
#pragma unroll
  for (int k = 0; k < 5; ++k) {
    f32x2v o; o[0] = lg[2 * k]; o[1] = lg[2 * k + 1];
    *(f32x2v*)(logout + (size_t)(i0 + r) * NCLASS + c0 + (k << 1)) = o;
  }
  // log_softmax over 40 classes held by 4 consecutive lanes
  float mx = lg[0];
#pragma unroll
  for (int k = 1; k < 10; ++k) mx = fmaxf(mx, lg[k]);
  mx = fmaxf(mx, __shfl_xor(mx, 1));
  mx = fmaxf(mx, __shfl_xor(mx, 2));
  float sm = 0.0f;
#pragma unroll
  for (int k = 0; k < 10; ++k) sm += expf(lg[k] - mx);
  sm += __shfl_xor(sm, 1);
  sm += __shfl_xor(sm, 2);
  const float lse = mx + logf(sm);
#pragma unroll
  for (int k = 0; k < 5; ++k) {
    f32x2v o; o[0] = lg[2 * k] - lse; o[1] = lg[2 * k + 1] - lse;
    *(f32x2v*)(lpout + (size_t)(i0 + r) * NCLASS + c0 + (k << 1)) = o;
  }
}

// ---------------------------------------------------------------------------
extern "C" void kernel_launch(void* const* d_in, const int* in_sizes, int n_in,
                              void* d_out, int out_size, void* d_ws, size_t ws_size,
                              hipStream_t stream)
{
  const float* x   = (const float*)d_in[0];
  const float* adj = (const float*)d_in[1];
  const float* W1  = (const float*)d_in[2];
  const float* b1  = (const float*)d_in[3];
  const float* W2  = (const float*)d_in[4];
  const float* b2  = (const float*)d_in[5];
  const float* Wl  = (const float*)d_in[6];
  const float* bl  = (const float*)d_in[7];

  float* out    = (float*)d_out;
  float* lp     = out;                                    // [N][40]
  float* h1     = out + (size_t)NTOT * NCLASS;            // [N][128]
  float* h2     = h1  + (size_t)NTOT * NHID;              // [N][128]
  float* logits = h2  + (size_t)NTOT * NHID;              // [N][40]

  char* ws = (char*)d_ws;
  unsigned short* xT  = (unsigned short*)ws;                       // 4 MB
  unsigned short* h1T = (unsigned short*)(ws + ((size_t)4 << 20)); // 4 MB
  float*          supp = (float*)(ws + ((size_t)8 << 20));         // P * 8 MB

  // split-K factor for the big GEMMs, limited by workspace
  int P = 4;
  const size_t base  = (size_t)8 << 20;
  const size_t part  = (size_t)NTOT * NHID * sizeof(float);
  if (ws_size < base + 2 * part)      P = 1;
  else if (ws_size < base + 4 * part) P = 2;
  const int kchunk = NTOT / P;

  xpose_cvt<<<dim3(NTOT / 64), dim3(256), 0, stream>>>(x, xT);
  gemm_adj<<<dim3(NTOT / 128, P), dim3(256), 0, stream>>>(adj, xT, supp, kchunk);
  layer1_kernel<<<dim3(NTOT / 64), dim3(256), 0, stream>>>(x, supp, P, W1, b1, h1, h1T);
  gemm_adj<<<dim3(NTOT / 128, P), dim3(256), 0, stream>>>(adj, h1T, supp, kchunk);
  layer2_head<<<dim3(NTOT / 64), dim3(256), 0, stream>>>(h1, supp, P, W2, b2, Wl, bl,
                                                         h2, logits, lp);
}